// Round 6
// baseline (737.014 us; speedup 1.0000x reference)
//
#include <hip/hip_runtime.h>
#include <hip/hip_bf16.h>
#include <hip/hip_fp16.h>

// GCN 2-layer inference, N=100000, E=1600000, F_IN=100, H=128, C=47.
// R6: revert to R3's wave-per-node contiguous-gather agg (it was AT the
// ~6 TB/s per-CU vmem ceiling; R4/R5 slicing lost 2x to address divergence).
// Changes vs R3: gemm2 BEFORE agg2 (agg2 gathers 96B rows not 256B);
// all kernels standalone at full occupancy (no LDS-throttled fusions);
// count/scatter do 4 edges/thread with int4 loads; single-block scan_one
// replaces 3 scan launches; dinv gathered per-edge in agg1 (L2-hot 400KB)
// so gemm1 is dependency-free.

constexpr int N    = 100000;
constexpr int E    = 1600000;
constexpr int FIN  = 100;
constexpr int HD   = 128;
constexpr int C    = 47;
constexpr int C48  = 48;
constexpr int EN   = E + N;          // edges + self loops

// ---------- count: deg + per-edge slot (4 edges/thread, int4) ----------

__global__ __launch_bounds__(256) void count_pos(const int* __restrict__ dst,
                                                 int* __restrict__ cnt,
                                                 int* __restrict__ epos) {
    int t = blockIdx.x * 256 + threadIdx.x;
    int e0 = t * 4;
    if (e0 + 4 <= E) {
        int4 d = *(const int4*)(dst + e0);
        int p0 = atomicAdd(&cnt[d.x], 1);
        int p1 = atomicAdd(&cnt[d.y], 1);
        int p2 = atomicAdd(&cnt[d.z], 1);
        int p3 = atomicAdd(&cnt[d.w], 1);
        *(int4*)(epos + e0) = make_int4(p0, p1, p2, p3);
    } else {
        for (int e = e0; e < E; ++e) epos[e] = atomicAdd(&cnt[dst[e]], 1);
    }
}

// ---------- scan: rowptr + dinv + self-loop slots, one block ----------

__global__ __launch_bounds__(1024) void scan_one(const int* __restrict__ cnt,
                                                 int* __restrict__ rowptr,
                                                 float* __restrict__ dinv,
                                                 int* __restrict__ ep) {
    int t = threadIdx.x;
    constexpr int PER = (N + 1023) / 1024;   // 98
    int base = t * PER;
    int lim = base + PER < N ? base + PER : N;
    int s = 0;
    for (int i = base; i < lim; ++i) s += cnt[i] + 1;   // +1 self loop
    __shared__ int sm[1024];
    sm[t] = s;
    __syncthreads();
    for (int off = 1; off < 1024; off <<= 1) {
        int v = (t >= off) ? sm[t - off] : 0;
        __syncthreads();
        sm[t] += v;
        __syncthreads();
    }
    int excl = sm[t] - s;
    for (int i = base; i < lim; ++i) {
        int deg = cnt[i] + 1;
        rowptr[i] = excl;
        dinv[i] = rsqrtf((float)deg);
        ep[excl] = i;                 // self loop at slot 0
        excl += deg;
    }
    if (t == 0) rowptr[N] = EN;
}

// ---------- scatter: 4 edges/thread, no atomics ----------

__global__ __launch_bounds__(256) void scatter_edges(const int* __restrict__ ei,
                                                     const int* __restrict__ rowptr,
                                                     const int* __restrict__ epos,
                                                     int* __restrict__ ep) {
    int t = blockIdx.x * 256 + threadIdx.x;
    int e0 = t * 4;
    if (e0 + 4 <= E) {
        int4 s = *(const int4*)(ei + e0);
        int4 d = *(const int4*)(ei + E + e0);
        int4 p = *(const int4*)(epos + e0);
        int r0 = rowptr[d.x], r1 = rowptr[d.y], r2 = rowptr[d.z], r3 = rowptr[d.w];
        ep[r0 + 1 + p.x] = s.x;
        ep[r1 + 1 + p.y] = s.y;
        ep[r2 + 1 + p.z] = s.z;
        ep[r3 + 1 + p.w] = s.w;
    } else {
        for (int e = e0; e < E; ++e)
            ep[rowptr[ei[E + e]] + 1 + epos[e]] = ei[e];
    }
}

// ---------- GEMM1: xw[N,128] (fp16, UNscaled) = x[N,100] @ W1 ----------

__global__ __launch_bounds__(256) void gemm1(const float* __restrict__ x,
                                             const float* __restrict__ W1,
                                             __half* __restrict__ xwh) {
    __shared__ float sW[FIN * HD];     // 51.2 KB
    __shared__ float sX[64 * FIN];     // 25.6 KB
    int tx = threadIdx.x;
    size_t node0 = (size_t)blockIdx.x * 64;

    const float4* W4 = (const float4*)W1;
    for (int i = tx; i < FIN * HD / 4; i += 256) ((float4*)sW)[i] = W4[i];
    size_t base4 = node0 * FIN / 4;          // node0*100 divisible by 4
    const float4* x4 = (const float4*)x;
    for (int i = tx; i < 64 * FIN / 4; i += 256) {
        size_t g = base4 + i;
        ((float4*)sX)[i] = (g < (size_t)N * FIN / 4) ? x4[g]
                                                     : make_float4(0.f, 0.f, 0.f, 0.f);
    }
    __syncthreads();

    int col = (tx & 31) * 4;        // 0..124
    int nb  = (tx >> 5) * 8;        // 0..56
    float4 acc[8];
#pragma unroll
    for (int i = 0; i < 8; ++i) acc[i] = make_float4(0.f, 0.f, 0.f, 0.f);

    for (int k = 0; k < FIN; ++k) {
        float4 b = *(const float4*)&sW[k * HD + col];
#pragma unroll
        for (int i = 0; i < 8; ++i) {
            float a = sX[(nb + i) * FIN + k];
            acc[i].x = fmaf(a, b.x, acc[i].x);
            acc[i].y = fmaf(a, b.y, acc[i].y);
            acc[i].z = fmaf(a, b.z, acc[i].z);
            acc[i].w = fmaf(a, b.w, acc[i].w);
        }
    }
#pragma unroll
    for (int i = 0; i < 8; ++i) {
        size_t node = node0 + nb + i;
        if (node < (size_t)N) {
            union { __half2 h2[2]; uint2 u; } p;
            p.h2[0] = __floats2half2_rn(acc[i].x, acc[i].y);
            p.h2[1] = __floats2half2_rn(acc[i].z, acc[i].w);
            *(uint2*)&xwh[node * HD + col] = p.u;
        }
    }
}

// ---------- agg1: h[n] (fp16) = relu(b1 + dinv[n]*sum_j dinv[s_j]*xw[s_j]) ----------
// wave per node, half2 per lane, 8-deep independent gathers

__global__ __launch_bounds__(256) void agg1(const __half2* __restrict__ xh2,
                                            const int* __restrict__ rowptr,
                                            const int* __restrict__ ep,
                                            const float* __restrict__ dinv,
                                            const float* __restrict__ b1,
                                            __half2* __restrict__ hh2) {
    int node = blockIdx.x * 4 + (threadIdx.x >> 6);
    if (node >= N) return;
    int lane = threadIdx.x & 63;
    int beg = rowptr[node], end = rowptr[node + 1];
    float ax = 0.f, ay = 0.f;
    int j = beg;
    for (; j + 8 <= end; j += 8) {
        int s0 = ep[j+0], s1 = ep[j+1], s2 = ep[j+2], s3 = ep[j+3];
        int s4 = ep[j+4], s5 = ep[j+5], s6 = ep[j+6], s7 = ep[j+7];
        float d0 = dinv[s0], d1 = dinv[s1], d2 = dinv[s2], d3 = dinv[s3];
        float d4 = dinv[s4], d5 = dinv[s5], d6 = dinv[s6], d7 = dinv[s7];
        __half2 v0 = xh2[(size_t)s0 * 64 + lane];
        __half2 v1 = xh2[(size_t)s1 * 64 + lane];
        __half2 v2 = xh2[(size_t)s2 * 64 + lane];
        __half2 v3 = xh2[(size_t)s3 * 64 + lane];
        __half2 v4 = xh2[(size_t)s4 * 64 + lane];
        __half2 v5 = xh2[(size_t)s5 * 64 + lane];
        __half2 v6 = xh2[(size_t)s6 * 64 + lane];
        __half2 v7 = xh2[(size_t)s7 * 64 + lane];
        float2 f;
        f = __half22float2(v0); ax = fmaf(d0, f.x, ax); ay = fmaf(d0, f.y, ay);
        f = __half22float2(v1); ax = fmaf(d1, f.x, ax); ay = fmaf(d1, f.y, ay);
        f = __half22float2(v2); ax = fmaf(d2, f.x, ax); ay = fmaf(d2, f.y, ay);
        f = __half22float2(v3); ax = fmaf(d3, f.x, ax); ay = fmaf(d3, f.y, ay);
        f = __half22float2(v4); ax = fmaf(d4, f.x, ax); ay = fmaf(d4, f.y, ay);
        f = __half22float2(v5); ax = fmaf(d5, f.x, ax); ay = fmaf(d5, f.y, ay);
        f = __half22float2(v6); ax = fmaf(d6, f.x, ax); ay = fmaf(d6, f.y, ay);
        f = __half22float2(v7); ax = fmaf(d7, f.x, ax); ay = fmaf(d7, f.y, ay);
    }
    for (; j < end; ++j) {
        int s = ep[j];
        float d = dinv[s];
        float2 f = __half22float2(xh2[(size_t)s * 64 + lane]);
        ax = fmaf(d, f.x, ax);
        ay = fmaf(d, f.y, ay);
    }
    float dv = dinv[node];
    float2 bias = ((const float2*)b1)[lane];
    float rx = fmaxf(fmaf(dv, ax, bias.x), 0.f);
    float ry = fmaxf(fmaf(dv, ay, bias.y), 0.f);
    hh2[(size_t)node * 64 + lane] = __floats2half2_rn(rx, ry);
}

// ---------- GEMM2: xw2[N,48] (fp16) = dinv[n] * (h[N,128] @ W2[128,47]) ----------

__global__ __launch_bounds__(256) void gemm2(const __half2* __restrict__ hh2,
                                             const float* __restrict__ W2,
                                             const float* __restrict__ dinv,
                                             __half* __restrict__ xw2h) {
    __shared__ float sH[64 * 130];     // padded stride 130
    __shared__ float sW[HD * 48];      // padded to 48 cols
    int tx = threadIdx.x;
    size_t node0 = (size_t)blockIdx.x * 64;

    for (int i = tx; i < HD * 48; i += 256) {
        int k = i / 48, c = i - k * 48;
        sW[i] = (c < C) ? W2[k * C + c] : 0.f;
    }
    size_t base2 = node0 * 64;
    for (int i = tx; i < 64 * 64; i += 256) {
        size_t g = base2 + i;
        float2 f = (g < (size_t)N * 64) ? __half22float2(hh2[g]) : make_float2(0.f, 0.f);
        int row = i >> 6, c2 = (i & 63) * 2;
        sH[row * 130 + c2]     = f.x;
        sH[row * 130 + c2 + 1] = f.y;
    }
    __syncthreads();

    int c0 = (tx & 15) * 3;        // 0..45
    int nb = (tx >> 4) * 4;        // 0..60
    float acc[4][3] = {};
    for (int k = 0; k < HD; ++k) {
        float w0 = sW[k * 48 + c0];
        float w1 = sW[k * 48 + c0 + 1];
        float w2 = sW[k * 48 + c0 + 2];
#pragma unroll
        for (int i = 0; i < 4; ++i) {
            float a = sH[(nb + i) * 130 + k];
            acc[i][0] = fmaf(a, w0, acc[i][0]);
            acc[i][1] = fmaf(a, w1, acc[i][1]);
            acc[i][2] = fmaf(a, w2, acc[i][2]);
        }
    }
#pragma unroll
    for (int i = 0; i < 4; ++i) {
        size_t node = node0 + nb + i;
        if (node < (size_t)N) {
            float dv = dinv[node];
#pragma unroll
            for (int jj = 0; jj < 3; ++jj) {
                int c = c0 + jj;
                if (c < C) xw2h[node * C48 + c] = __float2half_rn(acc[i][jj] * dv);
            }
        }
    }
}

// ---------- agg2: out[n] = b2 + dinv[n] * sum_j xw2[src_j] ----------
// wave per node; lanes 0..47 carry features (48..63 read pad, never store)

__global__ __launch_bounds__(256) void agg2(const __half* __restrict__ xw2h,
                                            const int* __restrict__ rowptr,
                                            const int* __restrict__ ep,
                                            const float* __restrict__ dinv,
                                            const float* __restrict__ b2,
                                            float* __restrict__ out) {
    int node = blockIdx.x * 4 + (threadIdx.x >> 6);
    if (node >= N) return;
    int lane = threadIdx.x & 63;
    int beg = rowptr[node], end = rowptr[node + 1];
    float a = 0.f;
    int j = beg;
    for (; j + 8 <= end; j += 8) {
        int s0 = ep[j+0], s1 = ep[j+1], s2 = ep[j+2], s3 = ep[j+3];
        int s4 = ep[j+4], s5 = ep[j+5], s6 = ep[j+6], s7 = ep[j+7];
        __half v0 = xw2h[(size_t)s0 * C48 + lane];
        __half v1 = xw2h[(size_t)s1 * C48 + lane];
        __half v2 = xw2h[(size_t)s2 * C48 + lane];
        __half v3 = xw2h[(size_t)s3 * C48 + lane];
        __half v4 = xw2h[(size_t)s4 * C48 + lane];
        __half v5 = xw2h[(size_t)s5 * C48 + lane];
        __half v6 = xw2h[(size_t)s6 * C48 + lane];
        __half v7 = xw2h[(size_t)s7 * C48 + lane];
        a += __half2float(v0) + __half2float(v1) + __half2float(v2) + __half2float(v3)
           + __half2float(v4) + __half2float(v5) + __half2float(v6) + __half2float(v7);
    }
    for (; j < end; ++j) {
        a += __half2float(xw2h[(size_t)ep[j] * C48 + lane]);
    }
    if (lane < C) out[(size_t)node * C + lane] = fmaf(dinv[node], a, b2[lane]);
}

extern "C" void kernel_launch(void* const* d_in, const int* in_sizes, int n_in,
                              void* d_out, int out_size, void* d_ws, size_t ws_size,
                              hipStream_t stream) {
    const float* x  = (const float*)d_in[0];
    const int*   ei = (const int*)d_in[1];
    const float* W1 = (const float*)d_in[2];
    const float* b1 = (const float*)d_in[3];
    const float* W2 = (const float*)d_in[4];
    const float* b2 = (const float*)d_in[5];
    float* out = (float*)d_out;

    size_t off = 0;
    auto alloc = [&](size_t bytes) {
        void* p = (char*)d_ws + off;
        off += (bytes + 255) & ~(size_t)255;
        return p;
    };
    int*     cnt    = (int*)alloc((size_t)N * 4);
    int*     rowptr = (int*)alloc((size_t)(N + 1) * 4);
    int*     epos   = (int*)alloc((size_t)E * 4);
    float*   dinv   = (float*)alloc((size_t)N * 4);
    int*     ep     = (int*)alloc((size_t)EN * 4);
    __half*  xwh    = (__half*)alloc((size_t)N * HD * 2);
    __half*  hh     = (__half*)alloc((size_t)N * HD * 2);
    __half*  xw2h   = (__half*)alloc((size_t)N * C48 * 2 + 64);  // +pad for lane>47 reads
    (void)ws_size;

    int gE4 = (E / 4 + 255) / 256;   // 4 edges per thread

    hipMemsetAsync(cnt, 0, (size_t)N * 4, stream);
    gemm1<<<(N + 63) / 64, 256, 0, stream>>>(x, W1, xwh);
    count_pos<<<gE4, 256, 0, stream>>>(ei + E, cnt, epos);
    scan_one<<<1, 1024, 0, stream>>>(cnt, rowptr, dinv, ep);
    scatter_edges<<<gE4, 256, 0, stream>>>(ei, rowptr, epos, ep);
    agg1<<<(N + 3) / 4, 256, 0, stream>>>((const __half2*)xwh, rowptr, ep, dinv, b1, (__half2*)hh);
    gemm2<<<(N + 63) / 64, 256, 0, stream>>>((const __half2*)hh, W2, dinv, xw2h);
    agg2<<<(N + 3) / 4, 256, 0, stream>>>(xw2h, rowptr, ep, dinv, b2, out);
}